// Round 1
// baseline (1106.190 us; speedup 1.0000x reference)
//
#include <hip/hip_runtime.h>
#include <hip/hip_bf16.h>
#include <stdint.h>

typedef __bf16 bf16;
typedef __bf16 bf16x8 __attribute__((ext_vector_type(8)));
typedef float  f32x4  __attribute__((ext_vector_type(4)));

#define T_TOK 16384
#define DDIM  1024
#define FDIM  4096
#define NEXP  8

// ---------------- async global->LDS (width 16) ----------------
__device__ __forceinline__ void load_lds16(const bf16* g, bf16* l) {
  __builtin_amdgcn_global_load_lds(
      (const __attribute__((address_space(1))) void*)g,
      (__attribute__((address_space(3))) void*)l, 16, 0, 0);
}

// ---------------- router: fp32 logits + argmax + counts ----------------
// one wave per token; lane-parallel over D, shfl-reduce 8 expert accumulators
__global__ __launch_bounds__(256) void router_kernel(
    const float* __restrict__ x, const float* __restrict__ rw,
    const float* __restrict__ rb, int* __restrict__ idx, int* __restrict__ counts) {
  int wave = threadIdx.x >> 6, lane = threadIdx.x & 63;
  int t = blockIdx.x * 4 + wave;
  const float* xr = x + (size_t)t * DDIM;
  float acc[NEXP];
#pragma unroll
  for (int e = 0; e < NEXP; e++) acc[e] = 0.f;
  for (int i = 0; i < DDIM / 64; i++) {
    int d = i * 64 + lane;
    float xv = xr[d];
    const float4* rwp = (const float4*)(rw + (size_t)d * NEXP);
    float4 r0 = rwp[0], r1 = rwp[1];
    acc[0] += xv * r0.x; acc[1] += xv * r0.y; acc[2] += xv * r0.z; acc[3] += xv * r0.w;
    acc[4] += xv * r1.x; acc[5] += xv * r1.y; acc[6] += xv * r1.z; acc[7] += xv * r1.w;
  }
#pragma unroll
  for (int e = 0; e < NEXP; e++)
#pragma unroll
    for (int off = 32; off > 0; off >>= 1)
      acc[e] += __shfl_down(acc[e], off, 64);
  if (lane == 0) {
    float best = acc[0] + rb[0]; int bi = 0;
#pragma unroll
    for (int e = 1; e < NEXP; e++) {
      float v = acc[e] + rb[e];
      if (v > best) { best = v; bi = e; }   // strict > keeps first max (numpy argmax)
    }
    idx[t] = bi;
    atomicAdd(&counts[bi], 1);
  }
}

// ---------------- offsets prefix-sum + load-balance loss ----------------
__global__ void offs_loss_kernel(const int* __restrict__ counts,
                                 int* __restrict__ offs, float* __restrict__ loss_out) {
  int run = 0; float loss = 0.f;
  for (int e = 0; e < NEXP; e++) {
    offs[e] = run; run += counts[e];
    float u = (float)counts[e] / (float)T_TOK - 1.0f / (float)NEXP;
    loss += u * u;
  }
  *loss_out = loss / (float)NEXP;
}

// ---------------- scatter token ids into per-expert buckets ----------------
__global__ __launch_bounds__(256) void scatter_kernel(
    const int* __restrict__ idx, const int* __restrict__ offs,
    int* __restrict__ cursor, int* __restrict__ perm) {
  int t = blockIdx.x * 256 + threadIdx.x;
  int e = idx[t];
  int pos = atomicAdd(&cursor[e], 1);
  perm[offs[e] + pos] = t;
}

// ---------------- gather x rows (fp32) -> xg (bf16, expert order) ----------------
__global__ __launch_bounds__(256) void gather_kernel(
    const float* __restrict__ x, const int* __restrict__ perm, bf16* __restrict__ xg) {
  int wave = threadIdx.x >> 6, lane = threadIdx.x & 63;
  int p = blockIdx.x * 4 + wave;
  int t = perm[p];
  const float4* src = (const float4*)(x + (size_t)t * DDIM);
  bf16* dst = xg + (size_t)p * DDIM;
#pragma unroll
  for (int i = 0; i < 4; i++) {
    float4 v = src[i * 64 + lane];
    union { bf16 b[4]; uint64_t u; } cv;
    cv.b[0] = (bf16)v.x; cv.b[1] = (bf16)v.y; cv.b[2] = (bf16)v.z; cv.b[3] = (bf16)v.w;
    *(uint64_t*)(dst + (size_t)(i * 64 + lane) * 4) = cv.u;
  }
}

// ---------------- weight transpose+cast: src [E][R][C] fp32 -> dst [E][C][R] bf16 ----
__global__ __launch_bounds__(256) void transpose_cast_kernel(
    const float* __restrict__ src, bf16* __restrict__ dst, int R, int C) {
  __shared__ float tile[64][65];   // +1 pad: conflict-free column reads
  int e = blockIdx.z;
  src += (size_t)e * R * C;
  dst += (size_t)e * R * C;
  int tx = threadIdx.x & 63, ty = threadIdx.x >> 6;  // ty in 0..3
  int bx = blockIdx.x, by = blockIdx.y;
#pragma unroll
  for (int i = 0; i < 64; i += 4)
    tile[ty + i][tx] = src[(size_t)(by * 64 + ty + i) * C + bx * 64 + tx];
  __syncthreads();
#pragma unroll
  for (int i = 0; i < 64; i += 4)
    dst[(size_t)(bx * 64 + ty + i) * R + by * 64 + tx] = (bf16)tile[tx][ty + i];
}

// ---------------- grouped GEMM (m97-style 128x128 tile, BK=32) ----------------
// C[M,N] = A[M,K] * B^T[N,K]^T ; A rows are expert-contiguous (permuted order).
// LAYER1: epilogue = bias + relu -> h (bf16).  LAYER2: epilogue = bias -> scatter out (fp32).
template <int K, int N, bool LAYER1>
__global__ __launch_bounds__(256, 2) void moe_gemm(
    const bf16* __restrict__ Aall, const bf16* __restrict__ Ball,
    const float* __restrict__ bias, bf16* __restrict__ hout, float* __restrict__ yout,
    const int* __restrict__ counts, const int* __restrict__ offs,
    const int* __restrict__ perm) {
  int e = blockIdx.z;
  int rows = counts[e];
  int r0 = blockIdx.y * 128;
  if (r0 >= rows) return;              // block-uniform early exit
  int n0 = blockIdx.x * 128;
  int off = offs[e];
  const bf16* A = Aall + (size_t)off * K;
  const bf16* B = Ball + (size_t)e * (size_t)N * K;

  __shared__ bf16 lA[128 * 32];
  __shared__ bf16 lB[128 * 32];

  int t = threadIdx.x;
  int lane = t & 63, w = t >> 6;
  int wm = w & 1, wn = w >> 1;

  // staging: each thread moves 16B/round; 2 rounds for A (128 rows), 2 for B
  int srow = t >> 2;            // 0..63
  int skp  = (t & 3) * 8;       // k-offset in elements (0,8,16,24)
  int ar0 = r0 + srow, ar1 = r0 + srow + 64;
  const bf16* ga0 = A + (size_t)(ar0 < rows ? ar0 : 0) * K + skp;  // clamp pad rows in-bounds
  const bf16* ga1 = A + (size_t)(ar1 < rows ? ar1 : 0) * K + skp;
  const bf16* gb0 = B + (size_t)(n0 + srow) * K + skp;
  const bf16* gb1 = B + (size_t)(n0 + srow + 64) * K + skp;
  bf16* la0 = lA + t * 8;  bf16* la1 = lA + 2048 + t * 8;   // lds dst = waveBase + lane*16B
  bf16* lb0 = lB + t * 8;  bf16* lb1 = lB + 2048 + t * 8;

  f32x4 acc[4][4] = {};

  int am = wm * 64 + (lane & 15);
  int bn = wn * 64 + (lane & 15);
  int kq = (lane >> 4) * 8;

  for (int k0 = 0; k0 < K; k0 += 32) {
    __syncthreads();                       // previous iter's ds_reads drained
    load_lds16(ga0 + k0, la0);
    load_lds16(ga1 + k0, la1);
    load_lds16(gb0 + k0, lb0);
    load_lds16(gb1 + k0, lb1);
    __syncthreads();                       // vmcnt(0): tile landed in LDS
    bf16x8 af[4], bfr[4];
#pragma unroll
    for (int mi = 0; mi < 4; mi++) af[mi] = *(const bf16x8*)&lA[(am + mi * 16) * 32 + kq];
#pragma unroll
    for (int ni = 0; ni < 4; ni++) bfr[ni] = *(const bf16x8*)&lB[(bn + ni * 16) * 32 + kq];
#pragma unroll
    for (int mi = 0; mi < 4; mi++)
#pragma unroll
      for (int ni = 0; ni < 4; ni++)
        acc[mi][ni] = __builtin_amdgcn_mfma_f32_16x16x32_bf16(af[mi], bfr[ni], acc[mi][ni], 0, 0, 0);
  }

  // epilogue: C/D layout col=lane&15, row=(lane>>4)*4+reg  [m89/m91-verified]
  int cb = n0 + wn * 64 + (lane & 15);
  int rb = r0 + wm * 64 + ((lane >> 4) * 4);
#pragma unroll
  for (int ni = 0; ni < 4; ni++) {
    int col = cb + ni * 16;
    float bv = bias[e * N + col];
#pragma unroll
    for (int mi = 0; mi < 4; mi++) {
#pragma unroll
      for (int r = 0; r < 4; r++) {
        int row = rb + mi * 16 + r;
        if (row < rows) {
          float v = acc[mi][ni][r] + bv;
          if (LAYER1) {
            v = v > 0.f ? v : 0.f;
            hout[(size_t)(off + row) * N + col] = (bf16)v;
          } else {
            yout[(size_t)perm[off + row] * N + col] = v;
          }
        }
      }
    }
  }
}

// ---------------- launch ----------------
extern "C" void kernel_launch(void* const* d_in, const int* in_sizes, int n_in,
                              void* d_out, int out_size, void* d_ws, size_t ws_size,
                              hipStream_t stream) {
  const float* x   = (const float*)d_in[0];
  const float* rw  = (const float*)d_in[1];
  const float* rb  = (const float*)d_in[2];
  const float* w1  = (const float*)d_in[3];
  const float* b1  = (const float*)d_in[4];
  const float* w2  = (const float*)d_in[5];
  const float* b2  = (const float*)d_in[6];
  float* out = (float*)d_out;

  char* ws = (char*)d_ws;
  int* counts = (int*)(ws);         // 8 ints
  int* cursor = (int*)(ws + 64);    // 8 ints
  int* offs   = (int*)(ws + 128);   // 8 ints
  int* idx    = (int*)(ws + 4096);                       // T ints
  int* perm   = (int*)(ws + 4096 + 65536);               // T ints
  size_t base = 135168;                                   // 4096+2*65536 rounded up
  bf16* xg  = (bf16*)(ws + base);                         // 32 MB  [T,D]
  bf16* h   = (bf16*)(ws + base + 33554432ull);           // 128 MB [T,F]
  bf16* w1t = (bf16*)(ws + base + 33554432ull + 134217728ull);              // 64 MB [E,F,D]
  bf16* w2t = (bf16*)(ws + base + 33554432ull + 134217728ull + 67108864ull);// 64 MB [E,D,F]

  hipMemsetAsync(ws, 0, 256, stream);  // counts/cursor/offs
  router_kernel<<<T_TOK / 4, 256, 0, stream>>>(x, rw, rb, idx, counts);
  offs_loss_kernel<<<1, 1, 0, stream>>>(counts, offs, out + 16777216);
  scatter_kernel<<<T_TOK / 256, 256, 0, stream>>>(idx, offs, cursor, perm);
  gather_kernel<<<T_TOK / 4, 256, 0, stream>>>(x, perm, xg);
  transpose_cast_kernel<<<dim3(64, 16, 8), 256, 0, stream>>>(w1, w1t, 1024, 4096);
  transpose_cast_kernel<<<dim3(16, 64, 8), 256, 0, stream>>>(w2, w2t, 4096, 1024);
  moe_gemm<DDIM, FDIM, true><<<dim3(32, 128, 8), 256, 0, stream>>>(
      xg, w1t, b1, h, nullptr, counts, offs, perm);
  moe_gemm<FDIM, DDIM, false><<<dim3(8, 128, 8), 256, 0, stream>>>(
      h, w2t, b2, nullptr, out, counts, offs, perm);
}

// Round 2
// 901.075 us; speedup vs baseline: 1.2276x; 1.2276x over previous
//
#include <hip/hip_runtime.h>
#include <hip/hip_bf16.h>
#include <stdint.h>

typedef __bf16 bf16;
typedef __bf16 bf16x8 __attribute__((ext_vector_type(8)));
typedef float  f32x4  __attribute__((ext_vector_type(4)));

#define T_TOK 16384
#define DDIM  1024
#define FDIM  4096
#define NEXP  8

// ---------------- async global->LDS (width 16) ----------------
__device__ __forceinline__ void load_lds16(const bf16* g, bf16* l) {
  __builtin_amdgcn_global_load_lds(
      (const __attribute__((address_space(1))) void*)g,
      (__attribute__((address_space(3))) void*)l, 16, 0, 0);
}

// ---------------- router: fp32 logits + argmax (NO global atomics) ----------------
__global__ __launch_bounds__(256) void router_kernel(
    const float* __restrict__ x, const float* __restrict__ rw,
    const float* __restrict__ rb, int* __restrict__ idx) {
  int wave = threadIdx.x >> 6, lane = threadIdx.x & 63;
  int t = blockIdx.x * 4 + wave;
  const float* xr = x + (size_t)t * DDIM;
  float acc[NEXP];
#pragma unroll
  for (int e = 0; e < NEXP; e++) acc[e] = 0.f;
  for (int i = 0; i < DDIM / 64; i++) {
    int d = i * 64 + lane;
    float xv = xr[d];
    const float4* rwp = (const float4*)(rw + (size_t)d * NEXP);
    float4 r0 = rwp[0], r1 = rwp[1];
    acc[0] += xv * r0.x; acc[1] += xv * r0.y; acc[2] += xv * r0.z; acc[3] += xv * r0.w;
    acc[4] += xv * r1.x; acc[5] += xv * r1.y; acc[6] += xv * r1.z; acc[7] += xv * r1.w;
  }
#pragma unroll
  for (int e = 0; e < NEXP; e++)
#pragma unroll
    for (int off = 32; off > 0; off >>= 1)
      acc[e] += __shfl_down(acc[e], off, 64);
  if (lane == 0) {
    float best = acc[0] + rb[0]; int bi = 0;
#pragma unroll
    for (int e = 1; e < NEXP; e++) {
      float v = acc[e] + rb[e];
      if (v > best) { best = v; bi = e; }   // strict > == numpy first-max argmax
    }
    idx[t] = bi;
  }
}

// ---------------- histogram: LDS bins, 8 global atomics per block ----------------
__global__ __launch_bounds__(256) void hist_kernel(const int* __restrict__ idx,
                                                   int* __restrict__ counts) {
  __shared__ int h[NEXP];
  if (threadIdx.x < NEXP) h[threadIdx.x] = 0;
  __syncthreads();
  int t = blockIdx.x * 256 + threadIdx.x;
  atomicAdd(&h[idx[t]], 1);
  __syncthreads();
  if (threadIdx.x < NEXP) atomicAdd(&counts[threadIdx.x], h[threadIdx.x]);
}

// ---------------- offsets prefix-sum + load-balance loss ----------------
__global__ void offs_loss_kernel(const int* __restrict__ counts,
                                 int* __restrict__ offs, float* __restrict__ loss_out) {
  int run = 0; float loss = 0.f;
  for (int e = 0; e < NEXP; e++) {
    offs[e] = run; run += counts[e];
    float u = (float)counts[e] / (float)T_TOK - 1.0f / (float)NEXP;
    loss += u * u;
  }
  *loss_out = loss / (float)NEXP;
}

// ---------------- scatter: one cursor-atomic per (block, expert) ----------------
__global__ __launch_bounds__(256) void scatter_kernel(
    const int* __restrict__ idx, const int* __restrict__ offs,
    int* __restrict__ cursor, int* __restrict__ perm) {
  __shared__ int h[NEXP], base[NEXP];
  if (threadIdx.x < NEXP) h[threadIdx.x] = 0;
  __syncthreads();
  int t = blockIdx.x * 256 + threadIdx.x;
  int e = idx[t];
  int local = atomicAdd(&h[e], 1);        // LDS atomic
  __syncthreads();
  if (threadIdx.x < NEXP) base[threadIdx.x] = atomicAdd(&cursor[threadIdx.x], h[threadIdx.x]);
  __syncthreads();
  perm[offs[e] + base[e] + local] = t;
}

// ---------------- gather x rows (fp32) -> xg (bf16, expert order) ----------------
__global__ __launch_bounds__(256) void gather_kernel(
    const float* __restrict__ x, const int* __restrict__ perm, bf16* __restrict__ xg) {
  int wave = threadIdx.x >> 6, lane = threadIdx.x & 63;
  int p = blockIdx.x * 4 + wave;
  int t = perm[p];
  const float4* src = (const float4*)(x + (size_t)t * DDIM);
  bf16* dst = xg + (size_t)p * DDIM;
#pragma unroll
  for (int i = 0; i < 4; i++) {
    float4 v = src[i * 64 + lane];
    union { bf16 b[4]; uint64_t u; } cv;
    cv.b[0] = (bf16)v.x; cv.b[1] = (bf16)v.y; cv.b[2] = (bf16)v.z; cv.b[3] = (bf16)v.w;
    *(uint64_t*)(dst + (size_t)(i * 64 + lane) * 4) = cv.u;
  }
}

// ---------------- weight transpose+cast: [E][R][C] fp32 -> [E][C][R] bf16 ----------
__global__ __launch_bounds__(256) void transpose_cast_kernel(
    const float* __restrict__ src, bf16* __restrict__ dst, int R, int C) {
  __shared__ float tile[64][65];   // +1 pad: conflict-free transposed reads
  int e = blockIdx.z;
  src += (size_t)e * R * C;
  dst += (size_t)e * R * C;
  int tx = threadIdx.x & 63, ty = threadIdx.x >> 6;
  int bx = blockIdx.x, by = blockIdx.y;
#pragma unroll
  for (int i = 0; i < 64; i += 4)
    tile[ty + i][tx] = src[(size_t)(by * 64 + ty + i) * C + bx * 64 + tx];
  __syncthreads();
  // write phase: ushort4 (8B) stores; bank pattern is 2-way (free per m136)
  int orow = threadIdx.x >> 4;          // 0..15
  int oc4  = (threadIdx.x & 15) * 4;    // 0..60
#pragma unroll
  for (int i = 0; i < 64; i += 16) {
    int r = orow + i;                   // row within tile along C-dim
    union { bf16 b[4]; ushort4 u; } v;
#pragma unroll
    for (int j = 0; j < 4; j++) v.b[j] = (bf16)tile[oc4 + j][r];
    *(ushort4*)&dst[(size_t)(bx * 64 + r) * R + by * 64 + oc4] = v.u;
  }
}

// ---------------- grouped GEMM, expert->XCD pinned, GROUP_M swizzle --------------
// C[M,N] = A[M,K] * B[N,K]^T ; A rows expert-contiguous (permuted order).
// blockIdx.x: bit0-2 = expert (XCD round-robin heuristic), rest = swizzled (ytile,ntile)
template <int K, int N, int GROUP, bool LAYER1>
__global__ __launch_bounds__(256, 2) void moe_gemm(
    const bf16* __restrict__ Aall, const bf16* __restrict__ Ball,
    const float* __restrict__ bias, bf16* __restrict__ hout, float* __restrict__ yout,
    const int* __restrict__ counts, const int* __restrict__ offs,
    const int* __restrict__ perm) {
  constexpr int NT = N / 128;
  int b = blockIdx.x;
  int e = b & 7;
  int j = b >> 3;
  int group  = j / (GROUP * NT);
  int within = j % (GROUP * NT);
  int ytile  = group * GROUP + (within % GROUP);  // n-inner: GROUP A-tiles stay L2-hot
  int ntile  = within / GROUP;
  int rows = counts[e];
  int r0 = ytile * 128;
  if (r0 >= rows) return;
  int n0 = ntile * 128;
  int off = offs[e];
  const bf16* A = Aall + (size_t)off * K;
  const bf16* B = Ball + (size_t)e * (size_t)N * K;

  __shared__ bf16 lA[128 * 32];
  __shared__ bf16 lB[128 * 32];

  int t = threadIdx.x;
  int lane = t & 63, w = t >> 6;
  int wm = w & 1, wn = w >> 1;

  int srow = t >> 2;            // 0..63
  int skp  = (t & 3) * 8;       // k-offset (elements)
  int ar0 = r0 + srow, ar1 = r0 + srow + 64;
  const bf16* ga0 = A + (size_t)(ar0 < rows ? ar0 : 0) * K + skp;
  const bf16* ga1 = A + (size_t)(ar1 < rows ? ar1 : 0) * K + skp;
  const bf16* gb0 = B + (size_t)(n0 + srow) * K + skp;
  const bf16* gb1 = B + (size_t)(n0 + srow + 64) * K + skp;
  bf16* la0 = lA + t * 8;  bf16* la1 = lA + 2048 + t * 8;
  bf16* lb0 = lB + t * 8;  bf16* lb1 = lB + 2048 + t * 8;

  f32x4 acc[4][4] = {};

  int am = wm * 64 + (lane & 15);
  int bn = wn * 64 + (lane & 15);
  int kq = (lane >> 4) * 8;

  for (int k0 = 0; k0 < K; k0 += 32) {
    __syncthreads();
    load_lds16(ga0 + k0, la0);
    load_lds16(ga1 + k0, la1);
    load_lds16(gb0 + k0, lb0);
    load_lds16(gb1 + k0, lb1);
    __syncthreads();
    bf16x8 af[4], bfr[4];
#pragma unroll
    for (int mi = 0; mi < 4; mi++) af[mi] = *(const bf16x8*)&lA[(am + mi * 16) * 32 + kq];
#pragma unroll
    for (int ni = 0; ni < 4; ni++) bfr[ni] = *(const bf16x8*)&lB[(bn + ni * 16) * 32 + kq];
#pragma unroll
    for (int mi = 0; mi < 4; mi++)
#pragma unroll
      for (int ni = 0; ni < 4; ni++)
        acc[mi][ni] = __builtin_amdgcn_mfma_f32_16x16x32_bf16(af[mi], bfr[ni], acc[mi][ni], 0, 0, 0);
  }

  // epilogue: C/D layout col=lane&15, row=(lane>>4)*4+reg  [m89/m91-verified]
  int cb = n0 + wn * 64 + (lane & 15);
  int rb = r0 + wm * 64 + ((lane >> 4) * 4);
#pragma unroll
  for (int ni = 0; ni < 4; ni++) {
    int col = cb + ni * 16;
    float bv = bias[e * N + col];
#pragma unroll
    for (int mi = 0; mi < 4; mi++) {
#pragma unroll
      for (int r = 0; r < 4; r++) {
        int row = rb + mi * 16 + r;
        if (row < rows) {
          float v = acc[mi][ni][r] + bv;
          if (LAYER1) {
            v = v > 0.f ? v : 0.f;
            hout[(size_t)(off + row) * N + col] = (bf16)v;
          } else {
            yout[(size_t)perm[off + row] * N + col] = v;
          }
        }
      }
    }
  }
}

// ---------------- launch ----------------
extern "C" void kernel_launch(void* const* d_in, const int* in_sizes, int n_in,
                              void* d_out, int out_size, void* d_ws, size_t ws_size,
                              hipStream_t stream) {
  const float* x   = (const float*)d_in[0];
  const float* rw  = (const float*)d_in[1];
  const float* rb  = (const float*)d_in[2];
  const float* w1  = (const float*)d_in[3];
  const float* b1  = (const float*)d_in[4];
  const float* w2  = (const float*)d_in[5];
  const float* b2  = (const float*)d_in[6];
  float* out = (float*)d_out;

  char* ws = (char*)d_ws;
  int* counts = (int*)(ws);         // 8 ints
  int* cursor = (int*)(ws + 64);    // 8 ints
  int* offs   = (int*)(ws + 128);   // 8 ints
  int* idx    = (int*)(ws + 4096);                       // T ints
  int* perm   = (int*)(ws + 4096 + 65536);               // T ints
  size_t base = 135168;
  bf16* xg  = (bf16*)(ws + base);                         // 32 MB  [T,D]
  bf16* h   = (bf16*)(ws + base + 33554432ull);           // 128 MB [T,F]
  bf16* w1t = (bf16*)(ws + base + 33554432ull + 134217728ull);              // 64 MB [E,F,D]
  bf16* w2t = (bf16*)(ws + base + 33554432ull + 134217728ull + 67108864ull);// 64 MB [E,D,F]

  hipMemsetAsync(ws, 0, 256, stream);  // counts/cursor/offs
  router_kernel<<<T_TOK / 4, 256, 0, stream>>>(x, rw, rb, idx);
  hist_kernel<<<T_TOK / 256, 256, 0, stream>>>(idx, counts);
  offs_loss_kernel<<<1, 1, 0, stream>>>(counts, offs, out + 16777216);
  scatter_kernel<<<T_TOK / 256, 256, 0, stream>>>(idx, offs, cursor, perm);
  gather_kernel<<<T_TOK / 4, 256, 0, stream>>>(x, perm, xg);
  transpose_cast_kernel<<<dim3(64, 16, 8), 256, 0, stream>>>(w1, w1t, 1024, 4096);
  transpose_cast_kernel<<<dim3(16, 64, 8), 256, 0, stream>>>(w2, w2t, 4096, 1024);
  // layer1: K=1024, N=4096 (32 ntiles), GROUP_M=8 -> 2MB A-group resident per XCD-L2
  moe_gemm<DDIM, FDIM, 8, true><<<8 * 128 * 32, 256, 0, stream>>>(
      xg, w1t, b1, h, nullptr, counts, offs, perm);
  // layer2: K=4096, N=1024 (8 ntiles), GROUP_M=4 -> 4MB A-group resident
  moe_gemm<FDIM, DDIM, 4, false><<<8 * 128 * 8, 256, 0, stream>>>(
      h, w2t, b2, nullptr, out, counts, offs, perm);
}